// Round 4
// baseline (450.958 us; speedup 1.0000x reference)
//
#include <hip/hip_runtime.h>
#include <hip/hip_bf16.h>

// B=32, S=2048, H=512, fp32 in/out.
// scores = tanh(Y@W + b).w -> softmax(S) -> c_star = alpha@Y
// GEMM redesign: K=512 is small -> stage the ENTIRE B-slice (64 cols x 512 k,
// fp16, 64KB) in LDS ONCE per block, fragment-ordered (conflict-free b128
// reads). Persistent blocks: 512 blocks (8 nblk x 64), 2 blocks/CU, each
// handles 8 mblks. K-loop has ZERO barriers: A loads global->reg->cvt
// (Y is row-major k-contiguous = exact A-frag shape), B ds_reads, MFMA.
// Compiler free to pipeline the fully-unrolled 16-step loop.
// XCD decode: the 8 nblk-siblings of an mblk-slab group land on one XCD L2.
// Tail: softmax (sums 8 col-partials) + two-stage contiguous wsum.

#define Bsz 32
#define Ssz 2048
#define Hsz 512
#define Msz (Bsz * Ssz)   // 65536

using half8   = __attribute__((ext_vector_type(8))) _Float16;
using floatx4 = __attribute__((ext_vector_type(4))) float;

__device__ __forceinline__ void llds16(void* l, const void* g) {
  __builtin_amdgcn_global_load_lds((const __attribute__((address_space(1))) void*)g,
                                   (__attribute__((address_space(3))) void*)l, 16, 0, 0);
}

__device__ __forceinline__ float fast_tanh(float x) {
  const float e = __expf(2.f * x);
  return 1.f - 2.f / (e + 1.f);
}

// ---- W[k][n] fp32 -> Wt[n][k] fp16 (transpose + RNE cast) ----
__global__ __launch_bounds__(256) void wsplit_k(const float* __restrict__ W,
                                                _Float16* __restrict__ Wt) {
  __shared__ float tile[32][33];
  const int bx = blockIdx.x & 15, by = blockIdx.x >> 4;
  const int tx = threadIdx.x & 31, ty = threadIdx.x >> 5;
#pragma unroll
  for (int i = 0; i < 4; ++i)
    tile[ty + 8 * i][tx] = W[(size_t)(by * 32 + ty + 8 * i) * Hsz + bx * 32 + tx];
  __syncthreads();
#pragma unroll
  for (int i = 0; i < 4; ++i) {
    const int n = bx * 32 + ty + 8 * i;
    const int k = by * 32 + tx;
    Wt[(size_t)n * Hsz + k] = (_Float16)tile[tx][ty + 8 * i];
  }
}

// ---- GEMM + tanh.w partial-score epilogue (persistent, B-in-LDS-once) ----
__global__ __launch_bounds__(256, 2) void gemm_score_k(const float* __restrict__ Y,
                                                       const _Float16* __restrict__ Wt,
                                                       const float* __restrict__ bvec,
                                                       const float* __restrict__ wvec,
                                                       float* __restrict__ scores4) {
  // Fragment-ordered B: frag-block fb = ks*4+cf (1KB each): lane l holds
  // Wt[nblk*64 + cf*16 + (l&15)][ks*32 + (l>>4)*8 .. +8]  (8 fp16 = 16B)
  __shared__ __align__(16) _Float16 Bs[64 * 512];   // 64 KB
  const int tid = threadIdx.x;
  const int lane = tid & 63, wv = tid >> 6;
  const int lr = lane & 15, lq = lane >> 4;
  // Decode: x = XCD; per XCD 8 sibling-groups; group = 8 nblk-siblings
  // sharing the same 8 mblk slabs (L2 locality for Y re-reads).
  const int c = blockIdx.x;             // 0..511
  const int x = c & 7, grp = c >> 3;    // grp 0..63
  const int nblk = grp & 7;             // 0..7 (64-col slice)
  const int mbase = x * 64 + (grp >> 3) * 8;

  const _Float16* bW = Wt + (size_t)nblk * 64 * Hsz;

  // Stage B once: 64 frag-blocks / 4 waves = 16 llds per thread.
#pragma unroll
  for (int i = 0; i < 16; ++i) {
    const int fb = wv * 16 + i;                  // wave-uniform
    const int ks = fb >> 2, cf = fb & 3;
    llds16(&Bs[(size_t)fb * 512],
           bW + (size_t)(cf * 16 + lr) * Hsz + ks * 32 + lq * 8);
  }
  __syncthreads();   // one-time drain; no barriers after this

  float bb[4], ww[4];
#pragma unroll
  for (int cf = 0; cf < 4; ++cf) {
    const int col = nblk * 64 + cf * 16 + lr;
    bb[cf] = bvec[col];
    ww[cf] = wvec[col];
  }

  for (int m = 0; m < 8; ++m) {
    const int mblk = mbase + m;
    // A-frag rows: wave owns 32 rows (2 frags of 16).
    const float* aRow0 = Y + (size_t)(mblk * 128 + wv * 32 + lr) * Hsz + lq * 8;
    const float* aRow1 = aRow0 + (size_t)16 * Hsz;

    floatx4 acc[2][4];
#pragma unroll
    for (int rf = 0; rf < 2; ++rf)
#pragma unroll
      for (int cf = 0; cf < 4; ++cf)
        acc[rf][cf] = (floatx4){0.f, 0.f, 0.f, 0.f};

#pragma unroll
    for (int ks = 0; ks < 16; ++ks) {
      const float4 f00 = *(const float4*)(aRow0 + ks * 32);
      const float4 f01 = *(const float4*)(aRow0 + ks * 32 + 4);
      const float4 f10 = *(const float4*)(aRow1 + ks * 32);
      const float4 f11 = *(const float4*)(aRow1 + ks * 32 + 4);
      half8 a0, a1;
      a0[0] = (_Float16)f00.x; a0[1] = (_Float16)f00.y;
      a0[2] = (_Float16)f00.z; a0[3] = (_Float16)f00.w;
      a0[4] = (_Float16)f01.x; a0[5] = (_Float16)f01.y;
      a0[6] = (_Float16)f01.z; a0[7] = (_Float16)f01.w;
      a1[0] = (_Float16)f10.x; a1[1] = (_Float16)f10.y;
      a1[2] = (_Float16)f10.z; a1[3] = (_Float16)f10.w;
      a1[4] = (_Float16)f11.x; a1[5] = (_Float16)f11.y;
      a1[6] = (_Float16)f11.z; a1[7] = (_Float16)f11.w;
#pragma unroll
      for (int cf = 0; cf < 4; ++cf) {
        const half8 bf = *(const half8*)&Bs[(size_t)(ks * 4 + cf) * 512 + lane * 8];
        acc[0][cf] = __builtin_amdgcn_mfma_f32_16x16x32_f16(a0, bf, acc[0][cf], 0, 0, 0);
        acc[1][cf] = __builtin_amdgcn_mfma_f32_16x16x32_f16(a1, bf, acc[1][cf], 0, 0, 0);
      }
    }

    // Epilogue: v = sum_cols tanh(pre+b)*w; 16-lane shuffle reduce;
    // each wave owns all 64 cols of its rows -> no cross-wave combine.
#pragma unroll
    for (int rf = 0; rf < 2; ++rf) {
#pragma unroll
      for (int r = 0; r < 4; ++r) {
        float v = 0.f;
#pragma unroll
        for (int cf = 0; cf < 4; ++cf)
          v += fast_tanh(acc[rf][cf][r] + bb[cf]) * ww[cf];
        v += __shfl_xor(v, 1, 16);
        v += __shfl_xor(v, 2, 16);
        v += __shfl_xor(v, 4, 16);
        v += __shfl_xor(v, 8, 16);
        if (lr == 0)
          scores4[(size_t)nblk * Msz + mblk * 128 + wv * 32 + rf * 16 + lq * 4 + r] = v;
      }
    }
  }
}

// ---- softmax over S, summing 8 nblk partials -> alpha ----
__global__ __launch_bounds__(256) void softmax_k(const float* __restrict__ scores4,
                                                 const float* __restrict__ mask,
                                                 float* __restrict__ alpha) {
  const int b = blockIdx.x, t = threadIdx.x;
  const int lane = t & 63, wv = t >> 6;
  float s[8];
  float mx = -3.4e38f;
#pragma unroll
  for (int i = 0; i < 8; ++i) {
    const int idx = b * Ssz + i * 256 + t;
    float v = 0.f;
#pragma unroll
    for (int p = 0; p < 8; ++p) v += scores4[(size_t)p * Msz + idx];
    v -= 1000.f * (1.f - mask[idx]);
    s[i] = v;
    mx = fmaxf(mx, v);
  }
  for (int off = 32; off > 0; off >>= 1) mx = fmaxf(mx, __shfl_xor(mx, off, 64));
  __shared__ float rm[4], rs[4];
  if (lane == 0) rm[wv] = mx;
  __syncthreads();
  mx = fmaxf(fmaxf(rm[0], rm[1]), fmaxf(rm[2], rm[3]));
  float sum = 0.f;
#pragma unroll
  for (int i = 0; i < 8; ++i) {
    s[i] = __expf(s[i] - mx);
    sum += s[i];
  }
  for (int off = 32; off > 0; off >>= 1) sum += __shfl_xor(sum, off, 64);
  if (lane == 0) rs[wv] = sum;
  __syncthreads();
  sum = rs[0] + rs[1] + rs[2] + rs[3];
  const float inv = 1.f / sum;
#pragma unroll
  for (int i = 0; i < 8; ++i) alpha[b * Ssz + i * 256 + t] = s[i] * inv;
}

// ---- stage 1: partial sums of alpha*Y over 64-row slabs (contiguous 128KB) ----
__global__ __launch_bounds__(256) void wsum1_k(const float* __restrict__ alpha,
                                               const float* __restrict__ Y,
                                               float* __restrict__ partial) {
  const int b = blockIdx.x >> 5, sc = blockIdx.x & 31;
  const int t = threadIdx.x, lane = t & 63, wv = t >> 6;
  __shared__ float part[4 * 512];
  const int s0 = sc * 64 + wv * 16;
  const float* al = alpha + b * Ssz + s0;
  const float4* Yb = (const float4*)(Y + ((size_t)b * Ssz + s0) * Hsz);
  float a0 = 0.f, a1 = 0.f, a2 = 0.f, a3 = 0.f, a4 = 0.f, a5 = 0.f, a6 = 0.f, a7 = 0.f;
#pragma unroll 4
  for (int r = 0; r < 16; ++r) {
    const float a = al[r];
    const float4 y0 = Yb[r * 128 + lane * 2];
    const float4 y1 = Yb[r * 128 + lane * 2 + 1];
    a0 = fmaf(a, y0.x, a0); a1 = fmaf(a, y0.y, a1);
    a2 = fmaf(a, y0.z, a2); a3 = fmaf(a, y0.w, a3);
    a4 = fmaf(a, y1.x, a4); a5 = fmaf(a, y1.y, a5);
    a6 = fmaf(a, y1.z, a6); a7 = fmaf(a, y1.w, a7);
  }
  part[wv * 512 + 0 * 64 + lane] = a0;
  part[wv * 512 + 1 * 64 + lane] = a1;
  part[wv * 512 + 2 * 64 + lane] = a2;
  part[wv * 512 + 3 * 64 + lane] = a3;
  part[wv * 512 + 4 * 64 + lane] = a4;
  part[wv * 512 + 5 * 64 + lane] = a5;
  part[wv * 512 + 6 * 64 + lane] = a6;
  part[wv * 512 + 7 * 64 + lane] = a7;
  __syncthreads();
#pragma unroll
  for (int i = 0; i < 2; ++i) {
    const int h = i * 256 + t;
    const int idx = (h & 7) * 64 + (h >> 3);
    partial[((size_t)(b * 32 + sc)) * Hsz + h] =
        part[idx] + part[512 + idx] + part[1024 + idx] + part[1536 + idx];
  }
}

// ---- stage 2: out[b][h] = sum over 32 sc of partial ----
__global__ __launch_bounds__(256) void wsum2_k(const float* __restrict__ partial,
                                               float* __restrict__ out) {
  const int b = blockIdx.x >> 1;
  const int h = (blockIdx.x & 1) * 256 + threadIdx.x;
  float s = 0.f;
#pragma unroll 8
  for (int sc = 0; sc < 32; ++sc)
    s += partial[((size_t)(b * 32 + sc)) * Hsz + h];
  out[b * Hsz + h] = s;
}

extern "C" void kernel_launch(void* const* d_in, const int* in_sizes, int n_in,
                              void* d_out, int out_size, void* d_ws, size_t ws_size,
                              hipStream_t stream) {
  (void)in_sizes; (void)n_in; (void)out_size; (void)ws_size;
  const float* Y    = (const float*)d_in[0];
  const float* mask = (const float*)d_in[1];
  const float* W    = (const float*)d_in[2];
  const float* bvec = (const float*)d_in[3];
  const float* wvec = (const float*)d_in[4];
  float* out = (float*)d_out;

  char* ws = (char*)d_ws;
  _Float16* Wt   = (_Float16*)ws;                               // 512 KB
  float* scores4 = (float*)(ws + ((size_t)512 << 10));          // 2 MB (8 partial slabs)
  float* alpha   = (float*)(ws + ((size_t)2560 << 10));         // 256 KB
  float* partial = (float*)(ws + ((size_t)3 << 20));            // 2 MB  (total 5 MB)

  wsplit_k<<<256, 256, 0, stream>>>(W, Wt);
  gemm_score_k<<<512, 256, 0, stream>>>(Y, Wt, bvec, wvec, scores4);
  softmax_k<<<Bsz, 256, 0, stream>>>(scores4, mask, alpha);
  wsum1_k<<<Bsz * 32, 256, 0, stream>>>(alpha, Y, partial);
  wsum2_k<<<Bsz * 2, 256, 0, stream>>>(partial, out);
}

// Round 5
// 283.246 us; speedup vs baseline: 1.5921x; 1.5921x over previous
//
#include <hip/hip_runtime.h>
#include <hip/hip_bf16.h>

// B=32, S=2048, H=512, fp32 in/out.
// scores = tanh(Y@W + b).w -> softmax(S) -> c_star = alpha@Y
// GEMM: 128x128 tile, BK=32, 2-barrier loop (round-0 cadence), but A is
// WAVE-PRIVATE: each wave owns 32 rows x all 128 cols (acc[2][8]), so A
// loads go global->reg directly (same global traffic: each element once
// per block, L2/L3-served) and never touch LDS. Only B (fp16, 8KB/step)
// is LDS-staged via llds with the verified chunk-XOR swizzle.
// Cuts LDS bytes ~1.8x and fp32->fp16 cvts 2x vs round-0 (the two
// co-dominant costs: ~33us LDS + ~31us VALU of the 105us).
// Tail: softmax (4 col-partials) + wsum1 with atomicAdd epilogue (wsum2
// folded away; out zeroed via hipMemsetAsync).

#define Bsz 32
#define Ssz 2048
#define Hsz 512
#define Msz (Bsz * Ssz)   // 65536

using half8   = __attribute__((ext_vector_type(8))) _Float16;
using floatx4 = __attribute__((ext_vector_type(4))) float;

__device__ __forceinline__ void llds16(void* l, const void* g) {
  __builtin_amdgcn_global_load_lds((const __attribute__((address_space(1))) void*)g,
                                   (__attribute__((address_space(3))) void*)l, 16, 0, 0);
}

__device__ __forceinline__ float fast_tanh(float x) {
  const float e = __expf(2.f * x);
  return 1.f - 2.f / (e + 1.f);
}

// ---- W[k][n] fp32 -> Wt[n][k] fp16 (transpose + RNE cast) ----
__global__ __launch_bounds__(256) void wsplit_k(const float* __restrict__ W,
                                                _Float16* __restrict__ Wt) {
  __shared__ float tile[32][33];
  const int bx = blockIdx.x & 15, by = blockIdx.x >> 4;
  const int tx = threadIdx.x & 31, ty = threadIdx.x >> 5;
#pragma unroll
  for (int i = 0; i < 4; ++i)
    tile[ty + 8 * i][tx] = W[(size_t)(by * 32 + ty + 8 * i) * Hsz + bx * 32 + tx];
  __syncthreads();
#pragma unroll
  for (int i = 0; i < 4; ++i) {
    const int n = bx * 32 + ty + 8 * i;
    const int k = by * 32 + tx;
    Wt[(size_t)n * Hsz + k] = (_Float16)tile[tx][ty + 8 * i];
  }
}

// ---- GEMM + tanh.w partial-score epilogue ----
__global__ __launch_bounds__(256, 3) void gemm_score_k(const float* __restrict__ Y,
                                                       const _Float16* __restrict__ Wt,
                                                       const float* __restrict__ bvec,
                                                       const float* __restrict__ wvec,
                                                       float* __restrict__ scores4) {
  __shared__ __align__(16) _Float16 Bs[128 * 32];   // 8 KB fp16, chunk-swizzled
  const int tid = threadIdx.x;
  const int lane = tid & 63, wv = tid >> 6;
  const int lr = lane & 15, lq = lane >> 4;
  // XCD-aware decode: 4 nblk-siblings of one mblk share (g&7) -> same XCD L2.
  const int g = blockIdx.x;
  const int x = g & 7, q = g >> 3;
  const int nblk = q & 3;
  const int mblk = (q >> 2) * 8 + x;

  const _Float16* bW = Wt + (size_t)nblk * 128 * Hsz;

  // A: wave-private rows. Lane (lr,lq) of wave wv holds rows
  // mblk*128 + wv*32 + {0,16} + lr, k-slice [k0 + lq*8, +8) -- identical
  // lane mapping to the verified round-0 A-frag (row=..+lr, k=k0+lq*8).
  const float* aR0 = Y + (size_t)(mblk * 128 + wv * 32 + lr) * Hsz + lq * 8;
  const float* aR1 = aR0 + (size_t)16 * Hsz;

  floatx4 acc[2][8];
#pragma unroll
  for (int rf = 0; rf < 2; ++rf)
#pragma unroll
    for (int cf = 0; cf < 8; ++cf)
      acc[rf][cf] = (floatx4){0.f, 0.f, 0.f, 0.f};

  for (int it = 0; it < 16; ++it) {
    const int k0 = it * 32;
    // Stage B: 512 chunks of 16B (row=chunk>>2), gptr permuted within the
    // row's 64B window: at LDS slot s we store global chunk s^((row>>1)&3).
#pragma unroll
    for (int i = 0; i < 2; ++i) {
      const int cb = i * 256 + wv * 64;        // wave-uniform chunk base
      const int p = cb + lane;
      const int row = p >> 2;
      const int gc = (p & 3) ^ ((row >> 1) & 3);
      llds16(&Bs[cb * 8], bW + (size_t)row * Hsz + k0 + gc * 8);
    }
    __syncthreads();   // vmcnt drain waits only the 2 llds above

    // A: global->reg->cvt (RNE), no LDS round trip.
    const float4 f00 = *(const float4*)(aR0 + k0);
    const float4 f01 = *(const float4*)(aR0 + k0 + 4);
    const float4 f10 = *(const float4*)(aR1 + k0);
    const float4 f11 = *(const float4*)(aR1 + k0 + 4);
    half8 a0, a1;
    a0[0] = (_Float16)f00.x; a0[1] = (_Float16)f00.y;
    a0[2] = (_Float16)f00.z; a0[3] = (_Float16)f00.w;
    a0[4] = (_Float16)f01.x; a0[5] = (_Float16)f01.y;
    a0[6] = (_Float16)f01.z; a0[7] = (_Float16)f01.w;
    a1[0] = (_Float16)f10.x; a1[1] = (_Float16)f10.y;
    a1[2] = (_Float16)f10.z; a1[3] = (_Float16)f10.w;
    a1[4] = (_Float16)f11.x; a1[5] = (_Float16)f11.y;
    a1[6] = (_Float16)f11.z; a1[7] = (_Float16)f11.w;

#pragma unroll
    for (int cf = 0; cf < 8; ++cf) {
      const int nr = cf * 16 + lr;
      const half8 bf = *(const half8*)&Bs[nr * 32 + (lq ^ ((nr >> 1) & 3)) * 8];
      acc[0][cf] = __builtin_amdgcn_mfma_f32_16x16x32_f16(a0, bf, acc[0][cf], 0, 0, 0);
      acc[1][cf] = __builtin_amdgcn_mfma_f32_16x16x32_f16(a1, bf, acc[1][cf], 0, 0, 0);
    }
    __syncthreads();
  }

  // Epilogue: v = sum over all 128 cols of tanh(pre+b)*w; 16-lane shuffle
  // reduce; wave owns full rows -> direct per-lane store, no cross-wave LDS.
  float bb[8], ww[8];
#pragma unroll
  for (int cf = 0; cf < 8; ++cf) {
    const int col = nblk * 128 + cf * 16 + lr;
    bb[cf] = bvec[col];
    ww[cf] = wvec[col];
  }
#pragma unroll
  for (int rf = 0; rf < 2; ++rf) {
#pragma unroll
    for (int r = 0; r < 4; ++r) {
      float v = 0.f;
#pragma unroll
      for (int cf = 0; cf < 8; ++cf)
        v += fast_tanh(acc[rf][cf][r] + bb[cf]) * ww[cf];
      v += __shfl_xor(v, 1, 16);
      v += __shfl_xor(v, 2, 16);
      v += __shfl_xor(v, 4, 16);
      v += __shfl_xor(v, 8, 16);
      if (lr == 0)
        scores4[(size_t)nblk * Msz + mblk * 128 + wv * 32 + rf * 16 + lq * 4 + r] = v;
    }
  }
}

// ---- softmax over S, summing 4 nblk partials -> alpha ----
__global__ __launch_bounds__(256) void softmax_k(const float* __restrict__ scores4,
                                                 const float* __restrict__ mask,
                                                 float* __restrict__ alpha) {
  const int b = blockIdx.x, t = threadIdx.x;
  const int lane = t & 63, wv = t >> 6;
  float s[8];
  float mx = -3.4e38f;
#pragma unroll
  for (int i = 0; i < 8; ++i) {
    const int idx = b * Ssz + i * 256 + t;
    float v = scores4[idx] + scores4[Msz + idx] + scores4[2 * Msz + idx] + scores4[3 * Msz + idx];
    v -= 1000.f * (1.f - mask[idx]);
    s[i] = v;
    mx = fmaxf(mx, v);
  }
  for (int off = 32; off > 0; off >>= 1) mx = fmaxf(mx, __shfl_xor(mx, off, 64));
  __shared__ float rm[4], rs[4];
  if (lane == 0) rm[wv] = mx;
  __syncthreads();
  mx = fmaxf(fmaxf(rm[0], rm[1]), fmaxf(rm[2], rm[3]));
  float sum = 0.f;
#pragma unroll
  for (int i = 0; i < 8; ++i) {
    s[i] = __expf(s[i] - mx);
    sum += s[i];
  }
  for (int off = 32; off > 0; off >>= 1) sum += __shfl_xor(sum, off, 64);
  if (lane == 0) rs[wv] = sum;
  __syncthreads();
  sum = rs[0] + rs[1] + rs[2] + rs[3];
  const float inv = 1.f / sum;
#pragma unroll
  for (int i = 0; i < 8; ++i) alpha[b * Ssz + i * 256 + t] = s[i] * inv;
}

// ---- weighted sum of alpha*Y over 64-row slabs; atomicAdd into out ----
__global__ __launch_bounds__(256) void wsum1_k(const float* __restrict__ alpha,
                                               const float* __restrict__ Y,
                                               float* __restrict__ out) {
  const int b = blockIdx.x >> 5, sc = blockIdx.x & 31;
  const int t = threadIdx.x, lane = t & 63, wv = t >> 6;
  __shared__ float part[4 * 512];
  const int s0 = sc * 64 + wv * 16;
  const float* al = alpha + b * Ssz + s0;
  const float4* Yb = (const float4*)(Y + ((size_t)b * Ssz + s0) * Hsz);
  float a0 = 0.f, a1 = 0.f, a2 = 0.f, a3 = 0.f, a4 = 0.f, a5 = 0.f, a6 = 0.f, a7 = 0.f;
#pragma unroll 4
  for (int r = 0; r < 16; ++r) {
    const float a = al[r];
    const float4 y0 = Yb[r * 128 + lane * 2];
    const float4 y1 = Yb[r * 128 + lane * 2 + 1];
    a0 = fmaf(a, y0.x, a0); a1 = fmaf(a, y0.y, a1);
    a2 = fmaf(a, y0.z, a2); a3 = fmaf(a, y0.w, a3);
    a4 = fmaf(a, y1.x, a4); a5 = fmaf(a, y1.y, a5);
    a6 = fmaf(a, y1.z, a6); a7 = fmaf(a, y1.w, a7);
  }
  part[wv * 512 + 0 * 64 + lane] = a0;
  part[wv * 512 + 1 * 64 + lane] = a1;
  part[wv * 512 + 2 * 64 + lane] = a2;
  part[wv * 512 + 3 * 64 + lane] = a3;
  part[wv * 512 + 4 * 64 + lane] = a4;
  part[wv * 512 + 5 * 64 + lane] = a5;
  part[wv * 512 + 6 * 64 + lane] = a6;
  part[wv * 512 + 7 * 64 + lane] = a7;
  __syncthreads();
#pragma unroll
  for (int i = 0; i < 2; ++i) {
    const int h = i * 256 + t;
    const int idx = (h & 7) * 64 + (h >> 3);
    atomicAdd(&out[(size_t)b * Hsz + h],
              part[idx] + part[512 + idx] + part[1024 + idx] + part[1536 + idx]);
  }
}

extern "C" void kernel_launch(void* const* d_in, const int* in_sizes, int n_in,
                              void* d_out, int out_size, void* d_ws, size_t ws_size,
                              hipStream_t stream) {
  (void)in_sizes; (void)n_in; (void)out_size; (void)ws_size;
  const float* Y    = (const float*)d_in[0];
  const float* mask = (const float*)d_in[1];
  const float* W    = (const float*)d_in[2];
  const float* bvec = (const float*)d_in[3];
  const float* wvec = (const float*)d_in[4];
  float* out = (float*)d_out;

  char* ws = (char*)d_ws;
  _Float16* Wt   = (_Float16*)ws;                            // 512 KB
  float* scores4 = (float*)(ws + ((size_t)1 << 20));         // 1 MB (4 partials)
  float* alpha   = (float*)(ws + ((size_t)2 << 20));         // 256 KB

  hipMemsetAsync(out, 0, (size_t)Bsz * Hsz * sizeof(float), stream);
  wsplit_k<<<256, 256, 0, stream>>>(W, Wt);
  gemm_score_k<<<(Msz / 128) * 4, 256, 0, stream>>>(Y, Wt, bvec, wvec, scores4);
  softmax_k<<<Bsz, 256, 0, stream>>>(scores4, mask, alpha);
  wsum1_k<<<Bsz * 32, 256, 0, stream>>>(alpha, Y, out);
}

// Round 6
// 273.717 us; speedup vs baseline: 1.6475x; 1.0348x over previous
//
#include <hip/hip_runtime.h>
#include <hip/hip_bf16.h>

// B=32, S=2048, H=512, fp32 in/out.
// scores = tanh(Y@W + b).w -> softmax(S) -> c_star = alpha@Y
// GEMM: 128x128 tile, BK=32. A wave-private global->reg (raw fp32 held one
// iteration ahead, cvt fp16 at use). B fp16 double-buffered LDS via llds,
// chunk-XOR swizzled. TRUE counted-vmcnt pipeline: top wait vmcnt(6)
// retires only B(it); A(it) waits are compiler-inserted (vmcnt(2));
// B(it+1)+A(it+1) stay in flight across barriers; lgkmcnt(0) only after
// MFMAs. vmcnt NEVER drains to 0 in the loop. Epochs between raw
// s_barriers each contain one load group -> FIFO order unambiguous.
// Tail: red_k (masked score-sum + per-b {max, 1/sum}), wsum_k computes
// alpha inline and atomicAdds 64-row partial sums into out.

#define Bsz 32
#define Ssz 2048
#define Hsz 512
#define Msz (Bsz * Ssz)   // 65536

using half8   = __attribute__((ext_vector_type(8))) _Float16;
using floatx4 = __attribute__((ext_vector_type(4))) float;

__device__ __forceinline__ void llds16(void* l, const void* g) {
  __builtin_amdgcn_global_load_lds((const __attribute__((address_space(1))) void*)g,
                                   (__attribute__((address_space(3))) void*)l, 16, 0, 0);
}

__device__ __forceinline__ float fast_tanh(float x) {
  const float e = __expf(2.f * x);
  return 1.f - 2.f / (e + 1.f);
}

// ---- W[k][n] fp32 -> Wt[n][k] fp16 (transpose + RNE cast) ----
__global__ __launch_bounds__(256) void wsplit_k(const float* __restrict__ W,
                                                _Float16* __restrict__ Wt) {
  __shared__ float tile[32][33];
  const int bx = blockIdx.x & 15, by = blockIdx.x >> 4;
  const int tx = threadIdx.x & 31, ty = threadIdx.x >> 5;
#pragma unroll
  for (int i = 0; i < 4; ++i)
    tile[ty + 8 * i][tx] = W[(size_t)(by * 32 + ty + 8 * i) * Hsz + bx * 32 + tx];
  __syncthreads();
#pragma unroll
  for (int i = 0; i < 4; ++i) {
    const int n = bx * 32 + ty + 8 * i;
    const int k = by * 32 + tx;
    Wt[(size_t)n * Hsz + k] = (_Float16)tile[tx][ty + 8 * i];
  }
}

// ---- GEMM + tanh.w partial-score epilogue ----
__global__ __launch_bounds__(256, 3) void gemm_score_k(const float* __restrict__ Y,
                                                       const _Float16* __restrict__ Wt,
                                                       const float* __restrict__ bvec,
                                                       const float* __restrict__ wvec,
                                                       float* __restrict__ scores4) {
  __shared__ __align__(16) _Float16 Bs[2][128 * 32];   // 2 x 8 KB fp16, chunk-swizzled
  const int tid = threadIdx.x;
  const int lane = tid & 63, wv = tid >> 6;
  const int lr = lane & 15, lq = lane >> 4;
  // XCD-aware decode: 4 nblk-siblings of one mblk share (g&7) -> same XCD L2.
  const int g = blockIdx.x;
  const int x = g & 7, q = g >> 3;
  const int nblk = q & 3;
  const int mblk = (q >> 2) * 8 + x;

  const _Float16* bW = Wt + (size_t)nblk * 128 * Hsz;

  // B staging descriptors: 512 chunks of 16B (row=chunk>>2), gptr permuted
  // within the row's 64B window (slot s holds global chunk s^((row>>1)&3)).
  int bL[2]; const _Float16* bG[2];
#pragma unroll
  for (int i = 0; i < 2; ++i) {
    const int cb = i * 256 + wv * 64;        // wave-uniform chunk base
    const int p = cb + lane;
    const int row = p >> 2;
    const int gc = (p & 3) ^ ((row >> 1) & 3);
    bL[i] = cb * 8;
    bG[i] = bW + (size_t)row * Hsz + gc * 8;
  }

  // A: wave-private rows; lane (lr,lq) holds rows mblk*128+wv*32+{0,16}+lr,
  // k-slice [k0+lq*8, +8) -- verified round-0/5 A-frag lane mapping.
  const float* aR0 = Y + (size_t)(mblk * 128 + wv * 32 + lr) * Hsz + lq * 8;
  const float* aR1 = aR0 + (size_t)16 * Hsz;

  floatx4 acc[2][8];
#pragma unroll
  for (int rf = 0; rf < 2; ++rf)
#pragma unroll
    for (int cf = 0; cf < 8; ++cf)
      acc[rf][cf] = (floatx4){0.f, 0.f, 0.f, 0.f};

  // Prologue (epoch order pinned): B(0)->buf0 | A(0) | B(1)->buf1.
#pragma unroll
  for (int i = 0; i < 2; ++i) { llds16(&Bs[0][bL[i]], bG[i]); bG[i] += 32; }
  __builtin_amdgcn_sched_barrier(0);
  float4 f00 = *(const float4*)(aR0);
  float4 f01 = *(const float4*)(aR0 + 4);
  float4 f10 = *(const float4*)(aR1);
  float4 f11 = *(const float4*)(aR1 + 4);
  __builtin_amdgcn_sched_barrier(0);
#pragma unroll
  for (int i = 0; i < 2; ++i) { llds16(&Bs[1][bL[i]], bG[i]); bG[i] += 32; }

  for (int it = 0; it < 16; ++it) {
    // Outstanding (FIFO): B(it)2, A(it)4, [B(it+1)2 if it<15].
    // Retire B(it) only; leave the rest in flight.
    if (it < 15) asm volatile("s_waitcnt vmcnt(6)" ::: "memory");
    else         asm volatile("s_waitcnt vmcnt(4)" ::: "memory");
    __builtin_amdgcn_s_barrier();          // buf[it&1] ready for all waves

    // cvt A(it) (compiler inserts its own vmcnt(2) here, leaving B(it+1) in flight)
    half8 a0, a1;
    a0[0] = (_Float16)f00.x; a0[1] = (_Float16)f00.y;
    a0[2] = (_Float16)f00.z; a0[3] = (_Float16)f00.w;
    a0[4] = (_Float16)f01.x; a0[5] = (_Float16)f01.y;
    a0[6] = (_Float16)f01.z; a0[7] = (_Float16)f01.w;
    a1[0] = (_Float16)f10.x; a1[1] = (_Float16)f10.y;
    a1[2] = (_Float16)f10.z; a1[3] = (_Float16)f10.w;
    a1[4] = (_Float16)f11.x; a1[5] = (_Float16)f11.y;
    a1[6] = (_Float16)f11.z; a1[7] = (_Float16)f11.w;

    // Prefetch A(it+1) raw (full-iteration latency cover)
    if (it < 15) {
      const int k1 = (it + 1) * 32;
      f00 = *(const float4*)(aR0 + k1);
      f01 = *(const float4*)(aR0 + k1 + 4);
      f10 = *(const float4*)(aR1 + k1);
      f11 = *(const float4*)(aR1 + k1 + 4);
    }

    // B frags + MFMA: compiler interleaves ds_read/MFMA with fine lgkmcnt.
    const _Float16* Bsb = Bs[it & 1];
#pragma unroll
    for (int cf = 0; cf < 8; ++cf) {
      const int nr = cf * 16 + lr;
      const half8 bf = *(const half8*)&Bsb[nr * 32 + (lq ^ ((nr >> 1) & 3)) * 8];
      acc[0][cf] = __builtin_amdgcn_mfma_f32_16x16x32_f16(a0, bf, acc[0][cf], 0, 0, 0);
      acc[1][cf] = __builtin_amdgcn_mfma_f32_16x16x32_f16(a1, bf, acc[1][cf], 0, 0, 0);
    }

    // All my ds_reads done (free: MFMAs consumed them); barrier -> all waves
    // done reading buf[it&1]; then overwrite it with B(it+2).
    asm volatile("s_waitcnt lgkmcnt(0)" ::: "memory");
    __builtin_amdgcn_s_barrier();
    if (it < 14) {
#pragma unroll
      for (int i = 0; i < 2; ++i) { llds16(&Bs[it & 1][bL[i]], bG[i]); bG[i] += 32; }
    }
  }

  // Epilogue: v = sum over all 128 cols of tanh(pre+b)*w; 16-lane shuffle
  // reduce; wave owns full rows -> direct per-lane store.
  float bb[8], ww[8];
#pragma unroll
  for (int cf = 0; cf < 8; ++cf) {
    const int col = nblk * 128 + cf * 16 + lr;
    bb[cf] = bvec[col];
    ww[cf] = wvec[col];
  }
#pragma unroll
  for (int rf = 0; rf < 2; ++rf) {
#pragma unroll
    for (int r = 0; r < 4; ++r) {
      float v = 0.f;
#pragma unroll
      for (int cf = 0; cf < 8; ++cf)
        v += fast_tanh(acc[rf][cf][r] + bb[cf]) * ww[cf];
      v += __shfl_xor(v, 1, 16);
      v += __shfl_xor(v, 2, 16);
      v += __shfl_xor(v, 4, 16);
      v += __shfl_xor(v, 8, 16);
      if (lr == 0)
        scores4[(size_t)nblk * Msz + mblk * 128 + wv * 32 + rf * 16 + lq * 4 + r] = v;
    }
  }
}

// ---- reduce: masked score-sum, per-b max and 1/sum(exp) ----
__global__ __launch_bounds__(1024) void red_k(const float* __restrict__ scores4,
                                              const float* __restrict__ mask,
                                              float* __restrict__ ssum,
                                              float* __restrict__ minv) {
  const int b = blockIdx.x, t = threadIdx.x;
  const int lane = t & 63, w = t >> 6;   // 16 waves
  __shared__ float rm[16], rs[16];
  float v[2];
  float mx = -3.4e38f;
#pragma unroll
  for (int i = 0; i < 2; ++i) {
    const int idx = b * Ssz + i * 1024 + t;
    float s = scores4[idx] + scores4[Msz + idx] + scores4[2 * Msz + idx] + scores4[3 * Msz + idx];
    s -= 1000.f * (1.f - mask[idx]);
    ssum[idx] = s;
    v[i] = s;
    mx = fmaxf(mx, s);
  }
  for (int off = 32; off > 0; off >>= 1) mx = fmaxf(mx, __shfl_xor(mx, off, 64));
  if (lane == 0) rm[w] = mx;
  __syncthreads();
  mx = rm[0];
#pragma unroll
  for (int i = 1; i < 16; ++i) mx = fmaxf(mx, rm[i]);
  float sum = __expf(v[0] - mx) + __expf(v[1] - mx);
  for (int off = 32; off > 0; off >>= 1) sum += __shfl_xor(sum, off, 64);
  if (lane == 0) rs[w] = sum;
  __syncthreads();
  if (t == 0) {
    float tot = rs[0];
#pragma unroll
    for (int i = 1; i < 16; ++i) tot += rs[i];
    minv[b * 2]     = mx;
    minv[b * 2 + 1] = 1.f / tot;
  }
}

// ---- weighted sum: alpha computed inline; atomicAdd into out ----
__global__ __launch_bounds__(256) void wsum_k(const float* __restrict__ ssum,
                                              const float* __restrict__ minv,
                                              const float* __restrict__ Y,
                                              float* __restrict__ out) {
  const int b = blockIdx.x >> 5, sc = blockIdx.x & 31;
  const int t = threadIdx.x, lane = t & 63, wv = t >> 6;
  __shared__ float part[4 * 512];
  const int s0 = sc * 64 + wv * 16;
  const float mx  = minv[b * 2];
  const float inv = minv[b * 2 + 1];
  const float* sl = ssum + b * Ssz + s0;
  const float4* Yb = (const float4*)(Y + ((size_t)b * Ssz + s0) * Hsz);
  float a0 = 0.f, a1 = 0.f, a2 = 0.f, a3 = 0.f, a4 = 0.f, a5 = 0.f, a6 = 0.f, a7 = 0.f;
#pragma unroll 4
  for (int r = 0; r < 16; ++r) {
    const float a = __expf(sl[r] - mx) * inv;
    const float4 y0 = Yb[r * 128 + lane * 2];
    const float4 y1 = Yb[r * 128 + lane * 2 + 1];
    a0 = fmaf(a, y0.x, a0); a1 = fmaf(a, y0.y, a1);
    a2 = fmaf(a, y0.z, a2); a3 = fmaf(a, y0.w, a3);
    a4 = fmaf(a, y1.x, a4); a5 = fmaf(a, y1.y, a5);
    a6 = fmaf(a, y1.z, a6); a7 = fmaf(a, y1.w, a7);
  }
  part[wv * 512 + 0 * 64 + lane] = a0;
  part[wv * 512 + 1 * 64 + lane] = a1;
  part[wv * 512 + 2 * 64 + lane] = a2;
  part[wv * 512 + 3 * 64 + lane] = a3;
  part[wv * 512 + 4 * 64 + lane] = a4;
  part[wv * 512 + 5 * 64 + lane] = a5;
  part[wv * 512 + 6 * 64 + lane] = a6;
  part[wv * 512 + 7 * 64 + lane] = a7;
  __syncthreads();
#pragma unroll
  for (int i = 0; i < 2; ++i) {
    const int h = i * 256 + t;
    const int idx = (h & 7) * 64 + (h >> 3);
    atomicAdd(&out[(size_t)b * Hsz + h],
              part[idx] + part[512 + idx] + part[1024 + idx] + part[1536 + idx]);
  }
}

extern "C" void kernel_launch(void* const* d_in, const int* in_sizes, int n_in,
                              void* d_out, int out_size, void* d_ws, size_t ws_size,
                              hipStream_t stream) {
  (void)in_sizes; (void)n_in; (void)out_size; (void)ws_size;
  const float* Y    = (const float*)d_in[0];
  const float* mask = (const float*)d_in[1];
  const float* W    = (const float*)d_in[2];
  const float* bvec = (const float*)d_in[3];
  const float* wvec = (const float*)d_in[4];
  float* out = (float*)d_out;

  char* ws = (char*)d_ws;
  _Float16* Wt   = (_Float16*)ws;                            // 512 KB
  float* scores4 = (float*)(ws + ((size_t)1 << 20));         // 1 MB (4 partials)
  float* ssum    = (float*)(ws + ((size_t)2 << 20));         // 256 KB
  float* minv    = (float*)(ws + ((size_t)2304 << 10));      // 256 B

  hipMemsetAsync(out, 0, (size_t)Bsz * Hsz * sizeof(float), stream);
  wsplit_k<<<256, 256, 0, stream>>>(W, Wt);
  gemm_score_k<<<(Msz / 128) * 4, 256, 0, stream>>>(Y, Wt, bvec, wvec, scores4);
  red_k<<<Bsz, 1024, 0, stream>>>(scores4, mask, ssum, minv);
  wsum_k<<<Bsz * 32, 256, 0, stream>>>(ssum, minv, Y, out);
}